// Round 10
// baseline (525.764 us; speedup 1.0000x reference)
//
#include <hip/hip_runtime.h>
#include <math.h>

// InfoNCE: features (4096, 2048, 4) fp32.
// g=1024 groups, ni=4, t=4, n=16 rows/group, c=2048.
// f[g, j, c] = features[g*4 + (j%4), c, j/4]  -> float4 at (b_row, c) holds
// elements of rows {0,4,8,12} + (j%4) for component t = j/4.
//
// R10 = R9 with the GSTEP macro paste bug fixed (X##0.x pasted against the
// pp-number "0.x"); gram_step is now a template function (R8-proven form).
//   K1: grid 2048 = (group, c-half), block 128 thr = 2 waves.
//       Wave 0 owns pairs [0,68), wave 1 [68,136) -- both stream the SAME
//       c-half (2x redundancy stays inside one CU's L1, same block).
//       68 acc + depth-2 load pipeline ~= 108 VGPR -> 4 waves/SIMD;
//       4096 waves chip-wide = all resident, one generation, no barriers.
//       Per-pair finish via wave_sum64 (R6/R8-validated), owner-lane write
//       to psum[blk][pair].
//   K2: per group: S = psum[g,half0] + psum[g,half1]; normalize + InfoNCE
//       epilogue -> gloss[g]  (R3/R4-proven code, SPLIT=2).
//   K3: reduce 1024 -> out = -sum/48.

#define NGROUP 1024
#define C 2048           // float4 columns per row
#define NPAIR 136        // 16*17/2
#define HCUT 68          // pair split point
#define NSTEP 16         // 1024 c-half cols / 64 lanes

__device__ __forceinline__ constexpr int pair_idx(int i, int j) {
    return i * 16 - (i * (i - 1)) / 2 + (j - i);
}

template <int CTRL>
__device__ __forceinline__ float dpp_add(float x) {
    union { float f; int i; } a, b;
    a.f = x;
    b.i = __builtin_amdgcn_mov_dpp(a.i, CTRL, 0xf, 0xf, true);
    return a.f + b.f;
}

__device__ __forceinline__ float rowsum16(float x) {   // validated R6/R8
    x = dpp_add<0x121>(x);
    x = dpp_add<0x122>(x);
    x = dpp_add<0x124>(x);
    x = dpp_add<0x128>(x);
    return x;
}

__device__ __forceinline__ float wave_sum64(float x, int lane) {  // validated
    x = rowsum16(x);
    union { float f; int i; } u, v;
    u.f = x;
    v.i = __builtin_amdgcn_ds_swizzle(u.i, 0x401F);             // xor16
    x = u.f + v.f;
    u.f = x;
    v.i = __builtin_amdgcn_ds_bpermute((lane ^ 32) << 2, u.i);  // xor32
    return u.f + v.f;
}

// one Gram step over this wave's pair range (R8-validated filter pattern)
template <int LO, int HI>
__device__ __forceinline__ void gram_step(const float4 v0, const float4 v1,
                                          const float4 v2, const float4 v3,
                                          float (&acc)[HI - LO]) {
    const float r[16] = { v0.x, v1.x, v2.x, v3.x,
                          v0.y, v1.y, v2.y, v3.y,
                          v0.z, v1.z, v2.z, v3.z,
                          v0.w, v1.w, v2.w, v3.w };
#pragma unroll
    for (int i = 0; i < 16; ++i)
#pragma unroll
        for (int j = i; j < 16; ++j) {
            const int p = pair_idx(i, j);   // constant after unroll
            if (p >= LO && p < HI)          // compile-time folded
                acc[p - LO] = fmaf(r[i], r[j], acc[p - LO]);
        }
}

template <int LO, int HI>
__device__ __forceinline__ void accum_pairs(const float4* __restrict__ r0,
                                            float* __restrict__ dst,
                                            const int lane) {
    const float4* r1 = r0 + C;
    const float4* r2 = r1 + C;
    const float4* r3 = r2 + C;

    float acc[HI - LO];
#pragma unroll
    for (int q = 0; q < HI - LO; ++q) acc[q] = 0.f;

    float4 a0, a1, a2, a3, b0, b1, b2, b3;

    // depth-2 register pipeline over NSTEP=16 steps
    a0 = r0[0]; a1 = r1[0]; a2 = r2[0]; a3 = r3[0];
#pragma unroll
    for (int k = 0; k < 7; ++k) {
        const int s1 = (2 * k + 1) * 64, s2 = (2 * k + 2) * 64;
        b0 = r0[s1]; b1 = r1[s1]; b2 = r2[s1]; b3 = r3[s1];
        gram_step<LO, HI>(a0, a1, a2, a3, acc);   // step 2k
        a0 = r0[s2]; a1 = r1[s2]; a2 = r2[s2]; a3 = r3[s2];
        gram_step<LO, HI>(b0, b1, b2, b3, acc);   // step 2k+1
    }
    {
        const int s1 = 15 * 64;
        b0 = r0[s1]; b1 = r1[s1]; b2 = r2[s1]; b3 = r3[s1];
        gram_step<LO, HI>(a0, a1, a2, a3, acc);   // step 14
        gram_step<LO, HI>(b0, b1, b2, b3, acc);   // step 15
    }

    // finish each owned pair entirely in-wave; one owner-lane write
#pragma unroll
    for (int q = 0; q < HI - LO; ++q) {
        const float tot = wave_sum64(acc[q], lane);
        if (lane == ((LO + q) & 63)) dst[LO + q] = tot;
    }
}

__global__ __launch_bounds__(128, 4)
void infonce_partial_kernel(const float4* __restrict__ feats,
                            float* __restrict__ psum) {
    const int blk  = blockIdx.x;
    const int g    = blk >> 1;
    const int ch   = blk & 1;        // c-half
    const int tid  = threadIdx.x;
    const int lane = tid & 63;
    const int w    = tid >> 6;

    const float4* base = feats + (size_t)g * 4 * C + ch * (C / 2) + lane;
    float* dst = psum + (size_t)blk * NPAIR;

    if (w == 0) accum_pairs<0, HCUT>(base, dst, lane);
    else        accum_pairs<HCUT, NPAIR>(base, dst, lane);
}

__global__ __launch_bounds__(128)
void infonce_group_finish(const float* __restrict__ psum,
                          float* __restrict__ gloss) {
    const int g   = blockIdx.x;
    const int tid = threadIdx.x;

    __shared__ float S[16][17];
    __shared__ float rowloss[16];

    const float* p0 = psum + (size_t)(g * 2 + 0) * NPAIR;
    const float* p1 = psum + (size_t)(g * 2 + 1) * NPAIR;

    for (int p = tid; p < NPAIR; p += 128) {
        int i = 0, rem = p;
        while (rem >= 16 - i) { rem -= 16 - i; ++i; }
        const int j = i + rem;
        const float s = p0[p] + p1[p];
        S[i][j] = s;
        S[j][i] = s;
    }
    __syncthreads();

    if (tid < 16) {
        const int i = tid;
        const float inv_i = 1.0f / fmaxf(sqrtf(S[i][i]), 1e-12f);
        float lg[16];
        float expneg = 0.f;
#pragma unroll
        for (int j = 0; j < 16; ++j) {
            const float inv_j = 1.0f / fmaxf(sqrtf(S[j][j]), 1e-12f);
            lg[j] = (S[i][j] * inv_i * inv_j) * (1.0f / 0.07f);
            if ((j >> 2) != (i >> 2)) expneg += expf(lg[j]);   // negatives
        }
        float sum = 0.f;
#pragma unroll
        for (int j = 0; j < 16; ++j) {
            if ((j >> 2) == (i >> 2) && j != i)                // positives
                sum += lg[j] - logf(expneg + expf(lg[j]));
        }
        rowloss[i] = sum;
    }
    __syncthreads();

    if (tid == 0) {
        float t = 0.f;
#pragma unroll
        for (int i = 0; i < 16; ++i) t += rowloss[i];
        gloss[g] = t;
    }
}

__global__ void infonce_final_reduce(const float* __restrict__ gloss,
                                     float* __restrict__ out) {
    const int tid = threadIdx.x;
    float s = 0.f;
    for (int i = tid; i < NGROUP; i += 256) s += gloss[i];
    s += __shfl_xor(s, 1);
    s += __shfl_xor(s, 2);
    s += __shfl_xor(s, 4);
    s += __shfl_xor(s, 8);
    s += __shfl_xor(s, 16);
    s += __shfl_xor(s, 32);
    __shared__ float ws[4];
    const int lane = tid & 63, wid = tid >> 6;
    if (lane == 0) ws[wid] = s;
    __syncthreads();
    if (tid == 0) {
        const float t = ws[0] + ws[1] + ws[2] + ws[3];
        out[0] = -t / 48.0f;
    }
}

extern "C" void kernel_launch(void* const* d_in, const int* in_sizes, int n_in,
                              void* d_out, int out_size, void* d_ws, size_t ws_size,
                              hipStream_t stream) {
    const float4* feats = (const float4*)d_in[0];
    float* psum  = (float*)d_ws;                      // 2048*136 floats
    float* gloss = psum + (size_t)2 * NGROUP * NPAIR; // 1024 floats
    float* out   = (float*)d_out;

    infonce_partial_kernel<<<NGROUP * 2, 128, 0, stream>>>(feats, psum);
    infonce_group_finish<<<NGROUP, 128, 0, stream>>>(psum, gloss);
    infonce_final_reduce<<<1, 256, 0, stream>>>(gloss, out);
}